// Round 11
// baseline (183.936 us; speedup 1.0000x reference)
//
#include <hip/hip_runtime.h>

#define V 32000
#define B 64
#define T 512
#define H 1024

typedef short bf16x8 __attribute__((ext_vector_type(8)));
typedef float f32x4 __attribute__((ext_vector_type(4)));

__device__ inline unsigned short f2bf(float x) {
    unsigned int u = __float_as_uint(x);
    return (unsigned short)((u + 0x7FFFu + ((u >> 16) & 1u)) >> 16);
}

// ---------- fused prep: emb->bf16, h0->bf16, u2 partials ----------
__global__ void prep_misc(const int* __restrict__ tok, const float* __restrict__ emb,
                          const float* __restrict__ h0, unsigned short* __restrict__ xcat0,
                          unsigned short* __restrict__ xcat1, const float4* __restrict__ W4,
                          const float* __restrict__ v, float4* __restrict__ u2p) {
    int blk = blockIdx.x;
    int tid = threadIdx.x;
    if (blk < 256) {                       // emb -> xcat0 cols 1024..2047
        int idx = blk * 256 + tid;
        int b = idx >> 10, e = idx & 1023;
        xcat0[(size_t)b * 3072 + 1024 + e] = f2bf(emb[(size_t)tok[b] * 1024 + e]);
    } else if (blk < 768) {                // h0 both layers
        int idx = (blk - 256) * 256 + tid;
        int layer = idx >> 16;
        int r = idx & 65535;
        int b = r >> 10, k = r & 1023;
        float vv = h0[layer * 65536 + b * 1024 + k];
        if (layer == 0) xcat0[(size_t)b * 3072 + 2048 + k] = f2bf(vv);
        else            xcat1[(size_t)b * 2048 + 1024 + k] = f2bf(vv);
    } else {                               // u2 partials, hc = blk-768 (0..31)
        int hc = blk - 768;
        float4 acc = {0.f, 0.f, 0.f, 0.f};
#pragma unroll 4
        for (int i = 0; i < 32; ++i) {
            int h = hc * 32 + i;
            float vv = v[h];
            float4 w = W4[(size_t)h * 512 + 256 + tid];
            acc.x += vv * w.x; acc.y += vv * w.y; acc.z += vv * w.z; acc.w += vv * w.w;
        }
        u2p[hc * 256 + tid] = acc;
    }
}

__global__ void u2_reduce(const float4* __restrict__ u2p, float4* __restrict__ u2) {
    int k4 = threadIdx.x;
    float4 acc = {0.f, 0.f, 0.f, 0.f};
#pragma unroll
    for (int hc = 0; hc < 32; ++hc) {
        float4 p = u2p[hc * 256 + k4];
        acc.x += p.x; acc.y += p.y; acc.z += p.z; acc.w += p.w;
    }
    u2[k4] = acc;
}

// scores[b,t] = enc[t,b,:] . u2  (per-b constant part cancels in softmax)
__global__ void scores_kernel(const float4* __restrict__ enc, const float4* __restrict__ u2,
                              float* __restrict__ scores) {
    int wid = (blockIdx.x * blockDim.x + threadIdx.x) >> 6;
    int lane = threadIdx.x & 63;
    int b = wid >> 9;
    int t = wid & 511;
    const float4* p = enc + (size_t)(t * B + b) * (H / 4);
    float acc = 0.f;
#pragma unroll
    for (int i = 0; i < 4; ++i) {
        float4 a = p[lane + 64 * i];
        float4 u = u2[lane + 64 * i];
        acc += a.x * u.x + a.y * u.y + a.z * u.z + a.w * u.w;
    }
#pragma unroll
    for (int off = 32; off; off >>= 1) acc += __shfl_xor(acc, off);
    if (lane == 0) scores[b * T + t] = acc;
}

// fused softmax + context partial; each (b,tc) block recomputes row softmax locally
__global__ void ctx_fused(const float* __restrict__ scores, const float4* __restrict__ enc4,
                          float4* __restrict__ part, float* __restrict__ attn_out) {
    int b = blockIdx.x;      // 0..63
    int tc = blockIdx.y;     // 0..15
    int tid = threadIdx.x;   // 256
    int wid = tid >> 6, lane = tid & 63;
    __shared__ float red[4];
    __shared__ float wts[32];
    float s0 = scores[b * T + tid];
    float s1 = scores[b * T + tid + 256];
    float m = fmaxf(s0, s1);
#pragma unroll
    for (int off = 32; off; off >>= 1) m = fmaxf(m, __shfl_xor(m, off));
    if (lane == 0) red[wid] = m;
    __syncthreads();
    float mb = fmaxf(fmaxf(red[0], red[1]), fmaxf(red[2], red[3]));
    __syncthreads();
    float e = expf(s0 - mb) + expf(s1 - mb);
#pragma unroll
    for (int off = 32; off; off >>= 1) e += __shfl_xor(e, off);
    if (lane == 0) red[wid] = e;
    __syncthreads();
    float inv = 1.f / (red[0] + red[1] + red[2] + red[3]);
    if (tid < 32) {
        float w = expf(scores[b * T + tc * 32 + tid] - mb) * inv;
        wts[tid] = w;
        attn_out[b * T + tc * 32 + tid] = w;
    }
    __syncthreads();
    float4 acc = {0.f, 0.f, 0.f, 0.f};
#pragma unroll 4
    for (int t = 0; t < 32; ++t) {
        int tt = tc * 32 + t;
        float w = wts[t];
        float4 e4 = enc4[((size_t)tt * B + b) * 256 + tid];
        acc.x += w * e4.x; acc.y += w * e4.y; acc.z += w * e4.z; acc.w += w * e4.w;
    }
    part[(size_t)tc * 16384 + tid * 64 + b] = acc;
}

// reduce ctx partials -> bf16 rows of xcat0 (cols 0..1023)
__global__ void ctx_reduce_bf(const float4* __restrict__ part, unsigned short* __restrict__ xcat0) {
    int idx = blockIdx.x * 256 + threadIdx.x;   // 0..16383
    int b = idx >> 8, h4 = idx & 255;
    float4 acc = {0.f, 0.f, 0.f, 0.f};
#pragma unroll
    for (int tc = 0; tc < 16; ++tc) {
        float4 p = part[tc * 16384 + h4 * 64 + b];
        acc.x += p.x; acc.y += p.y; acc.z += p.z; acc.w += p.w;
    }
    unsigned short* d = xcat0 + (size_t)b * 3072 + h4 * 4;
    d[0] = f2bf(acc.x); d[1] = f2bf(acc.y); d[2] = f2bf(acc.z); d[3] = f2bf(acc.w);
}

// ---------- MFMA GEMM, W staged global->LDS via global_load_lds, dbuf ----------
struct MJob {
    const float* W1; int ldw1;
    const float* W2; int ldw2;
    int seg;                            // global k < seg -> W1 else W2
    const unsigned short* A; int lda;   // bf16 [64][lda]
    float* out; int ldo; long outz;     // out + z*outz
    const float* bias;                  // may be null
    int kblk;                           // K per z slice (multiple of 128)
};

template <int NT>
__global__ __launch_bounds__(256) void mfma_gemm(MJob job) {
    constexpr int CHB = NT * 512;                  // chunk bytes (NT rows x 128k x 4B)
    __shared__ __align__(16) char Wlds[2 * CHB];
    int tid = threadIdx.x;
    int l = tid & 63;
    int mt = __builtin_amdgcn_readfirstlane(tid >> 6);
    int l15 = l & 15, l4 = l >> 4;
    int n0 = blockIdx.x * NT;
    int kbase = blockIdx.z * job.kblk;
    float* outp = job.out + (size_t)blockIdx.z * job.outz;
    f32x4 acc[NT / 16];
#pragma unroll
    for (int i = 0; i < NT / 16; ++i) acc[i] = (f32x4){0.f, 0.f, 0.f, 0.f};
    int nch = job.kblk >> 7;

    auto stageW = [&](int kg, int bi) {
        const float* Wb; int ldw, koff;
        if (kg < job.seg) { Wb = job.W1; ldw = job.ldw1; koff = kg; }
        else              { Wb = job.W2; ldw = job.ldw2; koff = kg - job.seg; }
        char* base = &Wlds[bi * CHB];
#pragma unroll
        for (int i = 0; i < NT / 8; ++i) {
            int gl = i * 256 + tid;
            int row = gl >> 5, gp = gl & 31;
            int G = gp ^ (row & 7);
            const float* src = Wb + (size_t)(n0 + row) * ldw + koff + G * 4;
            char* dst = base + (i * 4096 + (tid & 192) * 16);   // wave-uniform base
            __builtin_amdgcn_global_load_lds(
                (const __attribute__((address_space(1))) void*)src,
                (__attribute__((address_space(3))) void*)dst, 16, 0, 0);
        }
    };

    stageW(kbase, 0);
    __syncthreads();
    int cur = 0;
    for (int c = 0; c < nch; ++c) {
        int kg = kbase + c * 128;
        bf16x8 af[4];
        const unsigned short* arow = job.A + (size_t)(mt * 16 + l15) * job.lda + kg + l4 * 8;
#pragma unroll
        for (int s = 0; s < 4; ++s) af[s] = *(const bf16x8*)(arow + s * 32);
        if (c + 1 < nch) stageW(kbase + (c + 1) * 128, cur ^ 1);
        const char* rb = &Wlds[cur * CHB];
#pragma unroll
        for (int jt = 0; jt < NT / 16; ++jt) {
            int row = jt * 16 + l15;
            const char* rbase = rb + row * 512;
            int x = row & 7;
#pragma unroll
            for (int s = 0; s < 4; ++s) {
                int G0 = 2 * l4 + 8 * s;
                uint4 wa = *(const uint4*)(rbase + ((G0 ^ x) << 4));
                uint4 wb = *(const uint4*)(rbase + (((G0 + 1) ^ x) << 4));
                union { bf16x8 f; unsigned int u[4]; } bu;
                bu.u[0] = __builtin_amdgcn_perm(wa.y, wa.x, 0x07060302u);
                bu.u[1] = __builtin_amdgcn_perm(wa.w, wa.z, 0x07060302u);
                bu.u[2] = __builtin_amdgcn_perm(wb.y, wb.x, 0x07060302u);
                bu.u[3] = __builtin_amdgcn_perm(wb.w, wb.z, 0x07060302u);
                acc[jt] = __builtin_amdgcn_mfma_f32_16x16x32_bf16(af[s], bu.f, acc[jt], 0, 0, 0);
            }
        }
        __syncthreads();
        cur ^= 1;
    }
#pragma unroll
    for (int jt = 0; jt < NT / 16; ++jt) {
        int n = n0 + jt * 16 + l15;
        float bv = job.bias ? job.bias[n] : 0.f;
#pragma unroll
        for (int r = 0; r < 4; ++r) {
            int m = mt * 16 + l4 * 4 + r;
            outp[(size_t)m * job.ldo + n] = acc[jt][r] + bv;
        }
    }
}

// sum gate partials [gz][64][4096] + biases -> lstm cell; emit bf16 h for next GEMM
__global__ void lstm_elem(const float* __restrict__ gp, int gz,
                          const float* __restrict__ b_ih, const float* __restrict__ b_hh,
                          const float* __restrict__ c_prev, float* __restrict__ h_out,
                          float* __restrict__ c_out, unsigned short* __restrict__ hbf,
                          int hbf_ld) {
    int idx = blockIdx.x * 256 + threadIdx.x;   // 0..65535
    int b = idx >> 10, k = idx & 1023;
    float g[4];
#pragma unroll
    for (int gt = 0; gt < 4; ++gt) {
        float s = b_ih[gt * 1024 + k] + b_hh[gt * 1024 + k];
        for (int z = 0; z < gz; ++z)
            s += gp[(size_t)z * 262144 + (size_t)b * 4096 + gt * 1024 + k];
        g[gt] = s;
    }
    float i_ = 1.f / (1.f + expf(-g[0]));
    float f_ = 1.f / (1.f + expf(-g[1]));
    float gg = tanhf(g[2]);
    float o_ = 1.f / (1.f + expf(-g[3]));
    float c = f_ * c_prev[b * 1024 + k] + i_ * gg;
    float h = o_ * tanhf(c);
    c_out[b * 1024 + k] = c;
    h_out[b * 1024 + k] = h;
    hbf[(size_t)b * hbf_ld + k] = f2bf(h);
}

// log-softmax partials over V per row, 16 chunks of 2000, float4 loads
__global__ void lse_partial(const float4* __restrict__ logits4, float* __restrict__ pm,
                            float* __restrict__ ps) {
    int bi = blockIdx.x;   // 0..1023
    int b = bi >> 4, c = bi & 15;
    int tid = threadIdx.x;
    const float4* row = logits4 + (size_t)b * 8000 + c * 500;
    float m = -1e30f, s = 0.f;
#pragma unroll
    for (int i = 0; i < 2; ++i) {
        int v = i * 256 + tid;
        if (v < 500) {
            float4 x = row[v];
            float m1 = fmaxf(fmaxf(x.x, x.y), fmaxf(x.z, x.w));
            if (m1 > m) { s = s * expf(m - m1); m = m1; }
            s += expf(x.x - m) + expf(x.y - m) + expf(x.z - m) + expf(x.w - m);
        }
    }
#pragma unroll
    for (int off = 32; off; off >>= 1) {
        float m2 = __shfl_xor(m, off);
        float s2 = __shfl_xor(s, off);
        float mn = fmaxf(m, m2);
        s = s * expf(m - mn) + s2 * expf(m2 - mn);
        m = mn;
    }
    __shared__ float mred[4], sred[4];
    int wid = tid >> 6, lane = tid & 63;
    if (lane == 0) { mred[wid] = m; sred[wid] = s; }
    __syncthreads();
    if (tid == 0) {
        float M = mred[0], S = sred[0];
        for (int i = 1; i < 4; ++i) {
            float mn = fmaxf(M, mred[i]);
            S = S * expf(M - mn) + sred[i] * expf(mred[i] - mn);
            M = mn;
        }
        pm[bi] = M;
        ps[bi] = S;
    }
}

// final combine (redundant per block) + subtract
__global__ void lse_sub(float4* __restrict__ logits4, const float* __restrict__ pm,
                        const float* __restrict__ ps) {
    int b = blockIdx.y;
    float M = pm[b * 16], S = ps[b * 16];
#pragma unroll
    for (int i = 1; i < 16; ++i) {
        float m2 = pm[b * 16 + i];
        float mn = fmaxf(M, m2);
        S = S * expf(M - mn) + ps[b * 16 + i] * expf(m2 - mn);
        M = mn;
    }
    float l = M + logf(S);
    int v4 = blockIdx.x * 256 + threadIdx.x;
    if (v4 < 8000) {
        float4 x = logits4[(size_t)b * 8000 + v4];
        x.x -= l; x.y -= l; x.z -= l; x.w -= l;
        logits4[(size_t)b * 8000 + v4] = x;
    }
}

extern "C" void kernel_launch(void* const* d_in, const int* in_sizes, int n_in,
                              void* d_out, int out_size, void* d_ws, size_t ws_size,
                              hipStream_t stream) {
    const int*   tok   = (const int*)d_in[0];
    const float* h0    = (const float*)d_in[1];
    const float* c0    = (const float*)d_in[2];
    const float* enc   = (const float*)d_in[3];
    const float* emb   = (const float*)d_in[4];
    const float* attnW = (const float*)d_in[5];
    // d_in[6] attn_b: constant over t -> cancels in softmax
    const float* attnv = (const float*)d_in[7];
    const float* w_ih0 = (const float*)d_in[8];
    const float* w_hh0 = (const float*)d_in[9];
    const float* b_ih0 = (const float*)d_in[10];
    const float* b_hh0 = (const float*)d_in[11];
    const float* w_ih1 = (const float*)d_in[12];
    const float* w_hh1 = (const float*)d_in[13];
    const float* b_ih1 = (const float*)d_in[14];
    const float* b_hh1 = (const float*)d_in[15];
    const float* out_W = (const float*)d_in[16];
    const float* out_b = (const float*)d_in[17];
    float* out = (float*)d_out;
    float* ws = (float*)d_ws;

    // ws layout (float slots)
    float* u2     = ws;                                       // 1024
    float* u2p    = ws + 1024;                                // 32768
    float* scores = ws + 33792;                               // 32768
    unsigned short* xcat0 = (unsigned short*)(ws + 66560);    // 64x3072 bf16
    unsigned short* xcat1 = (unsigned short*)(ws + 164864);   // 64x2048 bf16
    unsigned short* h2bf  = (unsigned short*)(ws + 230400);   // 64x1024 bf16
    float* pm     = ws + 263168;                              // 1024
    float* ps     = ws + 264192;                              // 1024
    float* part   = ws + 1048576;                             // 1,048,576 floats (4-8 MB)
    float* gpart  = ws + 2097152;                             // 8 x 262144 floats (8-16 MB)

    // outputs
    float* out_logits = out;                 // [64][32000]
    float* out_h1 = out + 2048000;
    float* out_h2 = out + 2113536;
    float* out_c1 = out + 2179072;
    float* out_c2 = out + 2244608;
    float* out_attn = out + 2310144;         // [64][1][512]

    prep_misc<<<800, 256, 0, stream>>>(tok, emb, h0, xcat0, xcat1,
                                       (const float4*)attnW, attnv, (float4*)u2p);
    u2_reduce<<<1, 256, 0, stream>>>((const float4*)u2p, (float4*)u2);
    scores_kernel<<<8192, 256, 0, stream>>>((const float4*)enc, (const float4*)u2, scores);
    ctx_fused<<<dim3(64, 16), 256, 0, stream>>>(scores, (const float4*)enc,
                                                (float4*)part, out_attn);
    ctx_reduce_bf<<<64, 256, 0, stream>>>((const float4*)part, xcat0);

    // layer 0: gates = [ctx|emb|h0(0)](K=3072) . [w_ih0|w_hh0]^T, ksplit 8 (kblk 384)
    {
        MJob j = {w_ih0, 2048, w_hh0, 1024, 2048, xcat0, 3072,
                  gpart, 4096, 262144L, nullptr, 384};
        mfma_gemm<64><<<dim3(64, 1, 8), 256, 0, stream>>>(j);
    }
    lstm_elem<<<256, 256, 0, stream>>>(gpart, 8, b_ih0, b_hh0, c0,
                                       out_h1, out_c1, xcat1, 2048);

    // layer 1: gates = [h1|h0(1)](K=2048) . [w_ih1|w_hh1]^T, ksplit 8 (kblk 256)
    {
        MJob j = {w_ih1, 1024, w_hh1, 1024, 1024, xcat1, 2048,
                  gpart, 4096, 262144L, nullptr, 256};
        mfma_gemm<64><<<dim3(64, 1, 8), 256, 0, stream>>>(j);
    }
    lstm_elem<<<256, 256, 0, stream>>>(gpart, 8, b_ih1, b_hh1, c0 + 65536,
                                       out_h2, out_c2, h2bf, 1024);

    // logits = h2(bf16) . out_W^T + out_b, NT=16 -> grid 2000, 8 blocks/CU
    {
        MJob j = {out_W, 1024, nullptr, 0, 1 << 30, h2bf, 1024,
                  out_logits, V, 0L, out_b, 1024};
        mfma_gemm<16><<<dim3(2000, 1, 1), 256, 0, stream>>>(j);
    }

    lse_partial<<<1024, 256, 0, stream>>>((const float4*)out_logits, pm, ps);
    lse_sub<<<dim3(32, 64), 256, 0, stream>>>((float4*)out_logits, pm, ps);
}

// Round 12
// 147.732 us; speedup vs baseline: 1.2451x; 1.2451x over previous
//
#include <hip/hip_runtime.h>

#define V 32000
#define B 64
#define T 512
#define H 1024

typedef short bf16x8 __attribute__((ext_vector_type(8)));
typedef float f32x4 __attribute__((ext_vector_type(4)));

__device__ inline unsigned short f2bf(float x) {
    unsigned int u = __float_as_uint(x);
    return (unsigned short)((u + 0x7FFFu + ((u >> 16) & 1u)) >> 16);
}

// ---------- fused prep: emb->bf16, h0->bf16, u2 partials ----------
__global__ void prep_misc(const int* __restrict__ tok, const float* __restrict__ emb,
                          const float* __restrict__ h0, unsigned short* __restrict__ xcat0,
                          unsigned short* __restrict__ xcat1, const float4* __restrict__ W4,
                          const float* __restrict__ v, float4* __restrict__ u2p) {
    int blk = blockIdx.x;
    int tid = threadIdx.x;
    if (blk < 256) {                       // emb -> xcat0 cols 1024..2047
        int idx = blk * 256 + tid;
        int b = idx >> 10, e = idx & 1023;
        xcat0[(size_t)b * 3072 + 1024 + e] = f2bf(emb[(size_t)tok[b] * 1024 + e]);
    } else if (blk < 768) {                // h0 both layers
        int idx = (blk - 256) * 256 + tid;
        int layer = idx >> 16;
        int r = idx & 65535;
        int b = r >> 10, k = r & 1023;
        float vv = h0[layer * 65536 + b * 1024 + k];
        if (layer == 0) xcat0[(size_t)b * 3072 + 2048 + k] = f2bf(vv);
        else            xcat1[(size_t)b * 2048 + 1024 + k] = f2bf(vv);
    } else {                               // u2 partials, hc = blk-768 (0..31)
        int hc = blk - 768;
        float4 acc = {0.f, 0.f, 0.f, 0.f};
#pragma unroll 4
        for (int i = 0; i < 32; ++i) {
            int h = hc * 32 + i;
            float vv = v[h];
            float4 w = W4[(size_t)h * 512 + 256 + tid];
            acc.x += vv * w.x; acc.y += vv * w.y; acc.z += vv * w.z; acc.w += vv * w.w;
        }
        u2p[hc * 256 + tid] = acc;
    }
}

__global__ void u2_reduce(const float4* __restrict__ u2p, float4* __restrict__ u2) {
    int k4 = threadIdx.x;
    float4 acc = {0.f, 0.f, 0.f, 0.f};
#pragma unroll
    for (int hc = 0; hc < 32; ++hc) {
        float4 p = u2p[hc * 256 + k4];
        acc.x += p.x; acc.y += p.y; acc.z += p.z; acc.w += p.w;
    }
    u2[k4] = acc;
}

// ---------- one-pass attention: scores + online softmax + context partials ----------
// grid (64 b, 16 tc); block 256 = 4 waves; each wave handles 8 consecutive t.
__global__ __launch_bounds__(256) void attn_fused(
    const float4* __restrict__ enc4, const float4* __restrict__ u2,
    float* __restrict__ scores, float2* __restrict__ pms, float4* __restrict__ ctxp) {
    int b = blockIdx.x;
    int tc = blockIdx.y;
    int tid = threadIdx.x;
    int wid = tid >> 6, lane = tid & 63;
    float4 u[4];
#pragma unroll
    for (int i = 0; i < 4; ++i) u[i] = u2[lane + 64 * i];
    float m = -1e30f, s = 0.f;
    float4 acc[4] = {{0,0,0,0},{0,0,0,0},{0,0,0,0},{0,0,0,0}};
    int t0 = tc * 32 + wid * 8;
    for (int tt = 0; tt < 8; ++tt) {
        int t = t0 + tt;
        const float4* e = enc4 + ((size_t)t * B + b) * 256;
        float4 e4[4];
#pragma unroll
        for (int i = 0; i < 4; ++i) e4[i] = e[lane + 64 * i];
        float d = 0.f;
#pragma unroll
        for (int i = 0; i < 4; ++i)
            d += e4[i].x * u[i].x + e4[i].y * u[i].y + e4[i].z * u[i].z + e4[i].w * u[i].w;
#pragma unroll
        for (int off = 32; off; off >>= 1) d += __shfl_xor(d, off);
        if (lane == 0) scores[b * T + t] = d;
        float mn = fmaxf(m, d);
        float sc = expf(m - mn);
        float w = expf(d - mn);
        s = s * sc + w;
#pragma unroll
        for (int i = 0; i < 4; ++i) {
            acc[i].x = acc[i].x * sc + w * e4[i].x;
            acc[i].y = acc[i].y * sc + w * e4[i].y;
            acc[i].z = acc[i].z * sc + w * e4[i].z;
            acc[i].w = acc[i].w * sc + w * e4[i].w;
        }
        m = mn;
    }
    __shared__ float4 lacc[4][256];
    __shared__ float lm[4], ls[4];
#pragma unroll
    for (int i = 0; i < 4; ++i) lacc[wid][lane + 64 * i] = acc[i];
    if (lane == 0) { lm[wid] = m; ls[wid] = s; }
    __syncthreads();
    float M = fmaxf(fmaxf(lm[0], lm[1]), fmaxf(lm[2], lm[3]));
    float e0 = expf(lm[0] - M), e1 = expf(lm[1] - M);
    float e2 = expf(lm[2] - M), e3 = expf(lm[3] - M);
    float S = ls[0] * e0 + ls[1] * e1 + ls[2] * e2 + ls[3] * e3;
    float4 c0 = lacc[0][tid], c1 = lacc[1][tid], c2 = lacc[2][tid], c3 = lacc[3][tid];
    float4 c;
    c.x = c0.x * e0 + c1.x * e1 + c2.x * e2 + c3.x * e3;
    c.y = c0.y * e0 + c1.y * e1 + c2.y * e2 + c3.y * e3;
    c.z = c0.z * e0 + c1.z * e1 + c2.z * e2 + c3.z * e3;
    c.w = c0.w * e0 + c1.w * e1 + c2.w * e2 + c3.w * e3;
    ctxp[((size_t)tc * B + b) * 256 + tid] = c;
    if (tid == 0) pms[tc * B + b] = make_float2(M, S);
}

// combine 16 chunk partials -> bf16 ctx (xcat0 cols 0..1023) + attn weights output
__global__ void attn_combine(const float4* __restrict__ ctxp, const float2* __restrict__ pms,
                             const float* __restrict__ scores, unsigned short* __restrict__ xcat0,
                             float* __restrict__ attn_out) {
    int b = blockIdx.x, tid = threadIdx.x;
    float M = -1e30f, S = 0.f;
#pragma unroll
    for (int tc = 0; tc < 16; ++tc) {
        float2 p = pms[tc * B + b];
        float mn = fmaxf(M, p.x);
        S = S * expf(M - mn) + p.y * expf(p.x - mn);
        M = mn;
    }
    float inv = 1.f / S;
    float4 c = {0.f, 0.f, 0.f, 0.f};
#pragma unroll
    for (int tc = 0; tc < 16; ++tc) {
        float w = expf(pms[tc * B + b].x - M);
        float4 v = ctxp[((size_t)tc * B + b) * 256 + tid];
        c.x += w * v.x; c.y += w * v.y; c.z += w * v.z; c.w += w * v.w;
    }
    c.x *= inv; c.y *= inv; c.z *= inv; c.w *= inv;
    unsigned short* d = xcat0 + (size_t)b * 3072 + tid * 4;
    d[0] = f2bf(c.x); d[1] = f2bf(c.y); d[2] = f2bf(c.z); d[3] = f2bf(c.w);
#pragma unroll
    for (int j = 0; j < 2; ++j) {
        int t = j * 256 + tid;
        attn_out[b * T + t] = expf(scores[b * T + t] - M) * inv;
    }
}

// ---------- MFMA GEMM, W staged global->LDS via global_load_lds, dbuf ----------
struct MJob {
    const float* W1; int ldw1;
    const float* W2; int ldw2;
    int seg;                            // global k < seg -> W1 else W2
    const unsigned short* A; int lda;   // bf16 [64][lda]
    float* out; int ldo; long outz;     // out + z*outz
    const float* bias;                  // may be null
    int kblk;                           // K per z slice (multiple of 128)
};

template <int NT>
__global__ __launch_bounds__(256) void mfma_gemm(MJob job) {
    constexpr int CHB = NT * 512;                  // chunk bytes (NT rows x 128k x 4B)
    __shared__ __align__(16) char Wlds[2 * CHB];
    int tid = threadIdx.x;
    int l = tid & 63;
    int mt = __builtin_amdgcn_readfirstlane(tid >> 6);
    int l15 = l & 15, l4 = l >> 4;
    int n0 = blockIdx.x * NT;
    int kbase = blockIdx.z * job.kblk;
    float* outp = job.out + (size_t)blockIdx.z * job.outz;
    f32x4 acc[NT / 16];
#pragma unroll
    for (int i = 0; i < NT / 16; ++i) acc[i] = (f32x4){0.f, 0.f, 0.f, 0.f};
    int nch = job.kblk >> 7;

    auto stageW = [&](int kg, int bi) {
        const float* Wb; int ldw, koff;
        if (kg < job.seg) { Wb = job.W1; ldw = job.ldw1; koff = kg; }
        else              { Wb = job.W2; ldw = job.ldw2; koff = kg - job.seg; }
        char* base = &Wlds[bi * CHB];
#pragma unroll
        for (int i = 0; i < NT / 8; ++i) {
            int gl = i * 256 + tid;
            int row = gl >> 5, gp = gl & 31;
            int G = gp ^ (row & 7);
            const float* src = Wb + (size_t)(n0 + row) * ldw + koff + G * 4;
            char* dst = base + (i * 4096 + (tid & 192) * 16);   // wave-uniform base
            __builtin_amdgcn_global_load_lds(
                (const __attribute__((address_space(1))) void*)src,
                (__attribute__((address_space(3))) void*)dst, 16, 0, 0);
        }
    };

    stageW(kbase, 0);
    __syncthreads();
    int cur = 0;
    for (int c = 0; c < nch; ++c) {
        int kg = kbase + c * 128;
        bf16x8 af[4];
        const unsigned short* arow = job.A + (size_t)(mt * 16 + l15) * job.lda + kg + l4 * 8;
#pragma unroll
        for (int s = 0; s < 4; ++s) af[s] = *(const bf16x8*)(arow + s * 32);
        if (c + 1 < nch) stageW(kbase + (c + 1) * 128, cur ^ 1);
        const char* rb = &Wlds[cur * CHB];
#pragma unroll
        for (int jt = 0; jt < NT / 16; ++jt) {
            int row = jt * 16 + l15;
            const char* rbase = rb + row * 512;
            int x = row & 7;
#pragma unroll
            for (int s = 0; s < 4; ++s) {
                int G0 = 2 * l4 + 8 * s;
                uint4 wa = *(const uint4*)(rbase + ((G0 ^ x) << 4));
                uint4 wb = *(const uint4*)(rbase + (((G0 + 1) ^ x) << 4));
                union { bf16x8 f; unsigned int u[4]; } bu;
                bu.u[0] = __builtin_amdgcn_perm(wa.y, wa.x, 0x07060302u);
                bu.u[1] = __builtin_amdgcn_perm(wa.w, wa.z, 0x07060302u);
                bu.u[2] = __builtin_amdgcn_perm(wb.y, wb.x, 0x07060302u);
                bu.u[3] = __builtin_amdgcn_perm(wb.w, wb.z, 0x07060302u);
                acc[jt] = __builtin_amdgcn_mfma_f32_16x16x32_bf16(af[s], bu.f, acc[jt], 0, 0, 0);
            }
        }
        __syncthreads();
        cur ^= 1;
    }
#pragma unroll
    for (int jt = 0; jt < NT / 16; ++jt) {
        int n = n0 + jt * 16 + l15;
        float bv = job.bias ? job.bias[n] : 0.f;
#pragma unroll
        for (int r = 0; r < 4; ++r) {
            int m = mt * 16 + l4 * 4 + r;
            outp[(size_t)m * job.ldo + n] = acc[jt][r] + bv;
        }
    }
}

// sum gate partials [gz][64][4096] + biases -> lstm cell; emit bf16 h for next GEMM
__global__ void lstm_elem(const float* __restrict__ gp, int gz,
                          const float* __restrict__ b_ih, const float* __restrict__ b_hh,
                          const float* __restrict__ c_prev, float* __restrict__ h_out,
                          float* __restrict__ c_out, unsigned short* __restrict__ hbf,
                          int hbf_ld) {
    int idx = blockIdx.x * 256 + threadIdx.x;   // 0..65535
    int b = idx >> 10, k = idx & 1023;
    float g[4];
#pragma unroll
    for (int gt = 0; gt < 4; ++gt) {
        float s = b_ih[gt * 1024 + k] + b_hh[gt * 1024 + k];
        for (int z = 0; z < gz; ++z)
            s += gp[(size_t)z * 262144 + (size_t)b * 4096 + gt * 1024 + k];
        g[gt] = s;
    }
    float i_ = 1.f / (1.f + expf(-g[0]));
    float f_ = 1.f / (1.f + expf(-g[1]));
    float gg = tanhf(g[2]);
    float o_ = 1.f / (1.f + expf(-g[3]));
    float c = f_ * c_prev[b * 1024 + k] + i_ * gg;
    float h = o_ * tanhf(c);
    c_out[b * 1024 + k] = c;
    h_out[b * 1024 + k] = h;
    hbf[(size_t)b * hbf_ld + k] = f2bf(h);
}

// log-softmax partials over V per row, 16 chunks of 2000, float4 loads
__global__ void lse_partial(const float4* __restrict__ logits4, float* __restrict__ pm,
                            float* __restrict__ ps) {
    int bi = blockIdx.x;   // 0..1023
    int b = bi >> 4, c = bi & 15;
    int tid = threadIdx.x;
    const float4* row = logits4 + (size_t)b * 8000 + c * 500;
    float m = -1e30f, s = 0.f;
#pragma unroll
    for (int i = 0; i < 2; ++i) {
        int v = i * 256 + tid;
        if (v < 500) {
            float4 x = row[v];
            float m1 = fmaxf(fmaxf(x.x, x.y), fmaxf(x.z, x.w));
            if (m1 > m) { s = s * expf(m - m1); m = m1; }
            s += expf(x.x - m) + expf(x.y - m) + expf(x.z - m) + expf(x.w - m);
        }
    }
#pragma unroll
    for (int off = 32; off; off >>= 1) {
        float m2 = __shfl_xor(m, off);
        float s2 = __shfl_xor(s, off);
        float mn = fmaxf(m, m2);
        s = s * expf(m - mn) + s2 * expf(m2 - mn);
        m = mn;
    }
    __shared__ float mred[4], sred[4];
    int wid = tid >> 6, lane = tid & 63;
    if (lane == 0) { mred[wid] = m; sred[wid] = s; }
    __syncthreads();
    if (tid == 0) {
        float M = mred[0], S = sred[0];
        for (int i = 1; i < 4; ++i) {
            float mn = fmaxf(M, mred[i]);
            S = S * expf(M - mn) + sred[i] * expf(mred[i] - mn);
            M = mn;
        }
        pm[bi] = M;
        ps[bi] = S;
    }
}

// final combine (redundant per block) + subtract
__global__ void lse_sub(float4* __restrict__ logits4, const float* __restrict__ pm,
                        const float* __restrict__ ps) {
    int b = blockIdx.y;
    float M = pm[b * 16], S = ps[b * 16];
#pragma unroll
    for (int i = 1; i < 16; ++i) {
        float m2 = pm[b * 16 + i];
        float mn = fmaxf(M, m2);
        S = S * expf(M - mn) + ps[b * 16 + i] * expf(m2 - mn);
        M = mn;
    }
    float l = M + logf(S);
    int v4 = blockIdx.x * 256 + threadIdx.x;
    if (v4 < 8000) {
        float4 x = logits4[(size_t)b * 8000 + v4];
        x.x -= l; x.y -= l; x.z -= l; x.w -= l;
        logits4[(size_t)b * 8000 + v4] = x;
    }
}

extern "C" void kernel_launch(void* const* d_in, const int* in_sizes, int n_in,
                              void* d_out, int out_size, void* d_ws, size_t ws_size,
                              hipStream_t stream) {
    const int*   tok   = (const int*)d_in[0];
    const float* h0    = (const float*)d_in[1];
    const float* c0    = (const float*)d_in[2];
    const float* enc   = (const float*)d_in[3];
    const float* emb   = (const float*)d_in[4];
    const float* attnW = (const float*)d_in[5];
    // d_in[6] attn_b: constant over t -> cancels in softmax
    const float* attnv = (const float*)d_in[7];
    const float* w_ih0 = (const float*)d_in[8];
    const float* w_hh0 = (const float*)d_in[9];
    const float* b_ih0 = (const float*)d_in[10];
    const float* b_hh0 = (const float*)d_in[11];
    const float* w_ih1 = (const float*)d_in[12];
    const float* w_hh1 = (const float*)d_in[13];
    const float* b_ih1 = (const float*)d_in[14];
    const float* b_hh1 = (const float*)d_in[15];
    const float* out_W = (const float*)d_in[16];
    const float* out_b = (const float*)d_in[17];
    float* out = (float*)d_out;
    float* ws = (float*)d_ws;

    // ws layout (float slots)
    float* u2     = ws;                                       // 1024
    float* u2p    = ws + 1024;                                // 32768
    float* scores = ws + 33792;                               // 32768
    float2* pms   = (float2*)(ws + 66560);                    // 1024 x2
    unsigned short* xcat0 = (unsigned short*)(ws + 68608);    // 64x3072 bf16
    unsigned short* xcat1 = (unsigned short*)(ws + 166912);   // 64x2048 bf16
    unsigned short* h2bf  = (unsigned short*)(ws + 232448);   // 64x1024 bf16
    float* pm     = ws + 265216;                              // 1024
    float* ps     = ws + 266240;                              // 1024

    // outputs
    float* out_logits = out;                 // [64][32000]
    float* out_h1 = out + 2048000;
    float* out_h2 = out + 2113536;
    float* out_c1 = out + 2179072;
    float* out_c2 = out + 2244608;
    float* out_attn = out + 2310144;         // [64][1][512]

    // scratch inside logits region (sequenced: ctxp -> gate partials -> logits)
    float* ctxp  = out;         // 16*64*256 float4 = 1,048,576 floats
    float* gpart = out;         // 4 * 262144 floats

    prep_misc<<<800, 256, 0, stream>>>(tok, emb, h0, xcat0, xcat1,
                                       (const float4*)attnW, attnv, (float4*)u2p);
    u2_reduce<<<1, 256, 0, stream>>>((const float4*)u2p, (float4*)u2);
    attn_fused<<<dim3(64, 16), 256, 0, stream>>>((const float4*)enc, (const float4*)u2,
                                                 scores, pms, (float4*)ctxp);
    attn_combine<<<64, 256, 0, stream>>>((const float4*)ctxp, pms, scores, xcat0, out_attn);

    // layer 0: gates = [ctx|emb|h0(0)](K=3072) . [w_ih0|w_hh0]^T, ksplit 4 (kblk 768)
    {
        MJob j = {w_ih0, 2048, w_hh0, 1024, 2048, xcat0, 3072,
                  gpart, 4096, 262144L, nullptr, 768};
        mfma_gemm<64><<<dim3(64, 1, 4), 256, 0, stream>>>(j);
    }
    lstm_elem<<<256, 256, 0, stream>>>(gpart, 4, b_ih0, b_hh0, c0,
                                       out_h1, out_c1, xcat1, 2048);

    // layer 1: gates = [h1|h0(1)](K=2048) . [w_ih1|w_hh1]^T, ksplit 4 (kblk 512)
    {
        MJob j = {w_ih1, 1024, w_hh1, 1024, 1024, xcat1, 2048,
                  gpart, 4096, 262144L, nullptr, 512};
        mfma_gemm<64><<<dim3(64, 1, 4), 256, 0, stream>>>(j);
    }
    lstm_elem<<<256, 256, 0, stream>>>(gpart, 4, b_ih1, b_hh1, c0 + 65536,
                                       out_h2, out_c2, h2bf, 1024);

    // logits = h2(bf16) . out_W^T + out_b, NT=32 -> grid 1000, ~4 blocks/CU
    {
        MJob j = {out_W, 1024, nullptr, 0, 1 << 30, h2bf, 1024,
                  out_logits, V, 0L, out_b, 1024};
        mfma_gemm<32><<<dim3(1000, 1, 1), 256, 0, stream>>>(j);
    }

    lse_partial<<<1024, 256, 0, stream>>>((const float4*)out_logits, pm, ps);
    lse_sub<<<dim3(32, 64), 256, 0, stream>>>((float4*)out_logits, pm, ps);
}